// Round 3
// baseline (1632.263 us; speedup 1.0000x reference)
//
#include <hip/hip_runtime.h>
#include <math.h>

// ---------------- problem constants ----------------
// b=1, t=16, ch_in=10, h=w=24, t_de=16, ch_de=12, K=5, N=25
// hw=576, M = 576*25 = 14400; out: 27648 + loss = 27649 floats

typedef __attribute__((ext_vector_type(8))) short sh8;
typedef __attribute__((ext_vector_type(4))) float f32x4;

// ---------------- workspace layout (byte offsets) ----------------
#define OFF_PART 0UL                   // 58,982,400 (max: convf 4 splits x 6400x576x4)
#define OFF_ACTX 58982400UL            // 5 chunks x 2 x 55296
#define OFF_AF1  59535360UL            // 32 x 2 x 55296
#define OFF_AF2  63074304UL
#define OFF_AF3  66613248UL
#define OFF_WTT  70152192UL            // 6400x576 fp32
#define OFF_DN   84897792UL            // 14400x192 fp32
#define OFF_OB   95956992UL            // 14400x48 fp32
#define OFF_MN   98721792UL            // 576x7 fp32
#define OFF_MX   98737920UL
#define OFF_LP   98754048UL            // 576 fp32
// total ~98.8 MB (same as round 2, known-safe)

#define CHUNK_BYTES 55296              // per-plane act chunk stride (688 pos x 80B, padded)

// ---------------- bf16 helpers ----------------
__device__ inline unsigned short bf16_rne(float f) {
    unsigned int u = __builtin_bit_cast(unsigned int, f);
    unsigned int r = (u + 0x7FFFu + ((u >> 16) & 1u)) >> 16;
    return (unsigned short)r;
}
__device__ inline void bf16_split(float v, unsigned short& h, unsigned short& l) {
    h = bf16_rne(v);
    float fh = __builtin_bit_cast(float, ((unsigned int)h) << 16);
    l = bf16_rne(v - fh);
}
__device__ inline void glds16(const void* gsrc, void* ldst) {
    __builtin_amdgcn_global_load_lds((const __attribute__((address_space(1))) void*)gsrc,
                                     (__attribute__((address_space(3))) void*)ldst, 16, 0, 0);
}

// ---------------- min/max per pixel for the 7 normalization groups ----------------
__global__ __launch_bounds__(64) void minmax_kernel(const float* __restrict__ design,
                                                    float* __restrict__ mn_o,
                                                    float* __restrict__ mx_o) {
    int p = blockIdx.x;
    int py = p / 24, px = p % 24;
    int lane = threadIdx.x;
    float mn[7], mx[7];
#pragma unroll
    for (int g = 0; g < 7; g++) { mn[g] = 1e30f; mx[g] = -1e30f; }
    for (int e = lane; e < 400; e += 64) {
        int n = e / 16, td = e % 16;
        int yy = py + n / 5 - 2, xx = px + n % 5 - 2;
        bool ok = (yy >= 0 && yy < 24 && xx >= 0 && xx < 24);
#pragma unroll
        for (int cd = 1; cd < 12; cd++) {
            float v = ok ? design[(td * 12 + cd) * 576 + yy * 24 + xx] : 0.0f;
            int g = (cd <= 3) ? 0 : (cd == 4) ? 1 : (cd <= 7) ? 2 : 3 + (cd - 8);
            mn[g] = fminf(mn[g], v);
            mx[g] = fmaxf(mx[g], v);
        }
    }
#pragma unroll
    for (int s = 32; s >= 1; s >>= 1) {
#pragma unroll
        for (int g = 0; g < 7; g++) {
            mn[g] = fminf(mn[g], __shfl_xor(mn[g], s));
            mx[g] = fmaxf(mx[g], __shfl_xor(mx[g], s));
        }
    }
    if (lane == 0) {
#pragma unroll
        for (int g = 0; g < 7; g++) {
            mn_o[p * 7 + g] = mn[g];
            mx_o[p * 7 + g] = mx[g];
        }
    }
}

// ---------------- normalized d: dn[p][n][td][cd] ----------------
__global__ void dnorm_kernel(const float* __restrict__ design,
                             const float* __restrict__ mn,
                             const float* __restrict__ mx,
                             float* __restrict__ dn) {
    int idx = blockIdx.x * 256 + threadIdx.x;
    if (idx >= 14400 * 192) return;
    int cd = idx % 12;
    int td = (idx / 12) % 16;
    int n  = (idx / 192) % 25;
    int p  = idx / 4800;
    int py = p / 24, px = p % 24;
    int yy = py + n / 5 - 2, xx = px + n % 5 - 2;
    float v = (yy >= 0 && yy < 24 && xx >= 0 && xx < 24)
                  ? design[(td * 12 + cd) * 576 + yy * 24 + xx] : 0.0f;
    if (cd >= 1) {
        int g = (cd <= 3) ? 0 : (cd == 4) ? 1 : (cd <= 7) ? 2 : 3 + (cd - 8);
        float a = mn[p * 7 + g], b = mx[p * 7 + g];
        v = (v - a) / (b - a + 0.001f);
    }
    dn[idx] = v;
}

// ---------------- activation -> padded bf16 hi/lo chunk layout ----------------
// per chunk c32: hi plane [688 pos][40 halves] then lo plane; pos = yp*26+xp over
// padded 26x26; border/pad entries zero. Coalesced reads, 16B writes.
__global__ __launch_bounds__(256) void fact_kernel(const float* __restrict__ src,  // [nsplit][cout][576] (or raw)
                                                   const float* __restrict__ bias, // may be null
                                                   char* __restrict__ actH,
                                                   int cout, int nsplit, int do_act) {
    int c32 = blockIdx.x, pg = blockIdx.y;
    int icg = threadIdx.x >> 6;        // wave -> 8-channel group
    int k   = threadIdx.x & 63;
    int pos = pg * 64 + k;
    if (pos >= 688) return;
    int y = pos / 26, x = pos % 26;
    bool valid = (pos < 676) && (y >= 1 && y <= 24) && (x >= 1 && x <= 24);
    int pix = valid ? ((y - 1) * 24 + (x - 1)) : 0;
    sh8 h8, l8;
#pragma unroll
    for (int e = 0; e < 8; ++e) {
        float v = 0.0f;
        if (valid) {
            int ch = c32 * 32 + icg * 8 + e;
            for (int sp = 0; sp < nsplit; ++sp)
                v += src[((long)sp * cout + ch) * 576 + pix];
            if (do_act) { v += bias[ch]; v = v >= 0.f ? v : 0.01f * v; }
        }
        unsigned short h, l;
        bf16_split(v, h, l);
        h8[e] = (short)h; l8[e] = (short)l;
    }
    char* outp = actH + (long)c32 * 2 * CHUNK_BYTES + (long)pos * 80 + icg * 16;
    *(sh8*)outp = h8;
    *(sh8*)(outp + CHUNK_BYTES) = l8;
}

// ---------------- MFMA implicit-GEMM 3x3 conv (v2) ----------------
// Block: 128 oc x 288 px (12 out rows), 4 waves; wave (wo,wp) = 64 oc x 144 px = 4ot x 9j.
// Weights: per-lane direct fp32 loads (exactly its A-fragment, stride-9; L1-resident
// across the 9 taps), converted to bf16 hi/lo in-register, 1-tap prefetch. NO weight LDS.
// Acts: bf16 hi/lo staged per 32-ic chunk via global_load_lds (58,240 B), 2 blocks/CU.
// 3 products per k-chunk: Wh*Xh + Wl*Xh + Wh*Xl.
template<int CPS>
__global__ __launch_bounds__(256, 2)
void conv_mfma2_kernel(const char* __restrict__ actH,   // [ncc][2][CHUNK_BYTES]
                       const float* __restrict__ wgt,   // [cout][cin][9] fp32
                       float* __restrict__ part,        // [ksplit][cout][576]
                       int cin, int cout) {
    __shared__ __align__(1024) char sB[58368];   // hi @0 (29120B), lo @29120

    const int tid = threadIdx.x;
    const int lane = tid & 63;
    const int w = tid >> 6;
    const int wo = w >> 1, wp = w & 1;
    const int q = lane >> 4, ln15 = lane & 15;
    const int ocb = blockIdx.x, pxh = blockIdx.y, s = blockIdx.z;
    const int c0 = s * CPS;

    // B (acts) per-lane base addresses for the 9 j-tiles
    int pos0[9];
#pragma unroll
    for (int j = 0; j < 9; ++j) {
        int lp = wp * 144 + j * 16 + ln15;
        int r = lp / 24, c = lp % 24;
        pos0[j] = (r * 26 + c) * 80 + q * 16;
    }
    // A (weights) per-lane base float-index per ot
    int abase[4];
#pragma unroll
    for (int ot = 0; ot < 4; ++ot) {
        int oc = ocb * 128 + wo * 64 + ot * 16 + ln15;
        abase[ot] = oc * cin * 9;
    }
    const int icq = q * 8;

    f32x4 acc[4][9];
#pragma unroll
    for (int a = 0; a < 4; ++a)
#pragma unroll
        for (int j = 0; j < 9; ++j) acc[a][j] = f32x4{0.f, 0.f, 0.f, 0.f};

    // preload tap 0 of first chunk
    float wv[4][8];
#pragma unroll
    for (int ot = 0; ot < 4; ++ot)
#pragma unroll
        for (int e = 0; e < 8; ++e)
            wv[ot][e] = wgt[abase[ot] + (c0 * 32 + icq + e) * 9];

#pragma unroll 1
    for (int cc = c0; cc < c0 + CPS; ++cc) {
        __syncthreads();   // all waves done reading sB of previous chunk
        {
            const char* hsrc = actH + (long)cc * 2 * CHUNK_BYTES + pxh * 24960;
            for (int cI = w; cI < 57; cI += 4) {
                int off = cI * 1024 + lane * 16;
                if (off < 58240) {
                    const char* src = (off < 29120) ? (hsrc + off)
                                                    : (hsrc + CHUNK_BYTES + (off - 29120));
                    glds16(src, sB + cI * 1024);
                }
            }
        }
        asm volatile("s_waitcnt vmcnt(0)" ::: "memory");
        __syncthreads();

#pragma unroll 1
        for (int tap = 0; tap < 9; ++tap) {
            // convert current tap weights to bf16 hi/lo fragments
            sh8 ah[4], al[4];
#pragma unroll
            for (int ot = 0; ot < 4; ++ot)
#pragma unroll
                for (int e = 0; e < 8; ++e) {
                    unsigned short h, l;
                    bf16_split(wv[ot][e], h, l);
                    ah[ot][e] = (short)h; al[ot][e] = (short)l;
                }
            // prefetch next tap (or next chunk's tap 0)
            int ntap = tap + 1, ncc = cc;
            if (ntap == 9) { ntap = 0; ncc = (cc + 1 < c0 + CPS) ? cc + 1 : cc; }
            float wn[4][8];
            {
                const int icoff = (ncc * 32 + icq) * 9 + ntap;
#pragma unroll
                for (int ot = 0; ot < 4; ++ot)
#pragma unroll
                    for (int e = 0; e < 8; ++e)
                        wn[ot][e] = wgt[abase[ot] + icoff + e * 9];
            }
            // MFMA over 9 j-tiles
            const int doff = ((tap / 3) * 26 + (tap % 3)) * 80;
#pragma unroll
            for (int j = 0; j < 9; ++j) {
                sh8 bh = *(const sh8*)(sB + pos0[j] + doff);
                sh8 bl = *(const sh8*)(sB + 29120 + pos0[j] + doff);
#pragma unroll
                for (int ot = 0; ot < 4; ++ot) {
                    acc[ot][j] = __builtin_amdgcn_mfma_f32_16x16x32_bf16(ah[ot], bh, acc[ot][j], 0, 0, 0);
                    acc[ot][j] = __builtin_amdgcn_mfma_f32_16x16x32_bf16(al[ot], bh, acc[ot][j], 0, 0, 0);
                    acc[ot][j] = __builtin_amdgcn_mfma_f32_16x16x32_bf16(ah[ot], bl, acc[ot][j], 0, 0, 0);
                }
            }
#pragma unroll
            for (int ot = 0; ot < 4; ++ot)
#pragma unroll
                for (int e = 0; e < 8; ++e) wv[ot][e] = wn[ot][e];
        }
    }
    // epilogue: C row = oc (q*4+vr within tile), col = px (ln15)
#pragma unroll
    for (int ot = 0; ot < 4; ++ot)
#pragma unroll
        for (int j = 0; j < 9; ++j) {
            int pxg = pxh * 288 + wp * 144 + j * 16 + ln15;
#pragma unroll
            for (int vr = 0; vr < 4; ++vr) {
                int oc = ocb * 128 + wo * 64 + ot * 16 + q * 4 + vr;
                part[((long)s * cout + oc) * 576 + pxg] = acc[ot][j][vr];
            }
        }
}

// ---------------- tanh + sum 4 splits + transpose: part -> wtT[576][6400] ----------------
__global__ __launch_bounds__(256) void tanh_tr_kernel(const float* __restrict__ part,
                                                      const float* __restrict__ bias,
                                                      float* __restrict__ wtT) {
    __shared__ float tile[64][65];
    int oc0 = blockIdx.x * 64, p0 = blockIdx.y * 64;
    int tx = threadIdx.x, ty = threadIdx.y;
#pragma unroll
    for (int k = 0; k < 16; k++) {
        int row = ty + k * 4;
        float s = 0.f;
#pragma unroll
        for (int sp = 0; sp < 4; ++sp)
            s += part[((long)sp * 6400 + oc0 + row) * 576 + p0 + tx];
        tile[row][tx] = tanhf(s + bias[oc0 + row]);
    }
    __syncthreads();
#pragma unroll
    for (int k = 0; k < 16; k++) {
        int rr = ty + k * 4;
        wtT[(long)(p0 + rr) * 6400 + oc0 + tx] = tile[tx][rr];
    }
}

// ---------------- per-pixel stage: Wm, XTW, A, B, solve, o, loss partial ----------------
__global__ __launch_bounds__(256) void stagec_kernel(const float* __restrict__ dn,
                                                     const float* __restrict__ wtT,
                                                     const float* __restrict__ xin,
                                                     const float* __restrict__ gt,
                                                     float* __restrict__ ob,
                                                     float* __restrict__ lp) {
    int p = blockIdx.x;
    int py = p / 24, px = p % 24;
    int tid = threadIdx.x;
    __shared__ float sX[4800];
    __shared__ float sW[6400];
    __shared__ float sY[1200];
    __shared__ float sP[192];
    __shared__ float sXTW[192];
    __shared__ float sA[144];
    __shared__ float sB[36];
    __shared__ double dA[144];
    __shared__ double db[36];
    __shared__ float spara[36];
    __shared__ float sred[256];

    for (int e = tid; e < 4800; e += 256) sX[e] = dn[(long)p * 4800 + e];
    for (int e = tid; e < 6400; e += 256) sW[e] = wtT[(long)p * 6400 + e];
    for (int e = tid; e < 1200; e += 256) {
        int n = e / 48, t = (e % 48) / 3, ch = e % 3;
        int yy = py + n / 5 - 2, xx = px + n % 5 - 2;
        sY[e] = (yy >= 0 && yy < 24 && xx >= 0 && xx < 24)
                    ? xin[(t * 10 + ch) * 576 + yy * 24 + xx] : 0.0f;
    }
    if (tid < 144) sA[tid] = 0.0f;
    if (tid < 36) sB[tid] = 0.0f;
    __syncthreads();

    for (int n = 0; n < 25; n++) {
        const float* X = sX + n * 192;
        const float* W = sW + n * 256;
        if (tid < 192) {
            int c = tid >> 4, j = tid & 15;
            float s = 0.0f;
#pragma unroll
            for (int t = 0; t < 16; t++) s = fmaf(X[t * 12 + c], W[t * 16 + j], s);
            sP[tid] = s;
        }
        __syncthreads();
        if (tid < 192) {
            int c = tid >> 4, u = tid & 15;
            float s = X[u * 12 + c];
#pragma unroll
            for (int j = 0; j < 16; j++) s = fmaf(sP[c * 16 + j], W[u * 16 + j], s);
            sXTW[tid] = s;
        }
        __syncthreads();
        if (tid < 144) {
            int c = tid / 12, d2 = tid % 12;
            float s = 0.0f;
#pragma unroll
            for (int t = 0; t < 16; t++) s = fmaf(sXTW[c * 16 + t], X[t * 12 + d2], s);
            sA[tid] += s;
        } else if (tid < 180) {
            int e = tid - 144;
            int c = e / 3, ch = e % 3;
            float s = 0.0f;
#pragma unroll
            for (int t = 0; t < 16; t++) s = fmaf(sXTW[c * 16 + t], sY[n * 48 + t * 3 + ch], s);
            sB[e] += s;
        }
        __syncthreads();
    }

    if (tid < 144) dA[tid] = (double)sA[tid] + ((tid % 13 == 0) ? 0.01 : 0.0);
    if (tid < 36) db[tid] = (double)sB[tid];
    __syncthreads();

    if (tid == 0) {
        for (int kk = 0; kk < 12; kk++) {
            double d = dA[kk * 12 + kk];
            for (int q2 = 0; q2 < kk; q2++) d -= dA[kk * 12 + q2] * dA[kk * 12 + q2];
            d = sqrt(d);
            dA[kk * 12 + kk] = d;
            double inv = 1.0 / d;
            for (int i = kk + 1; i < 12; i++) {
                double s = dA[i * 12 + kk];
                for (int q2 = 0; q2 < kk; q2++) s -= dA[i * 12 + q2] * dA[kk * 12 + q2];
                dA[i * 12 + kk] = s * inv;
            }
        }
        for (int ch = 0; ch < 3; ch++) {
            double t2[12];
            for (int i = 0; i < 12; i++) {
                double s = db[i * 3 + ch];
                for (int q2 = 0; q2 < i; q2++) s -= dA[i * 12 + q2] * t2[q2];
                t2[i] = s / dA[i * 12 + i];
            }
            for (int i = 11; i >= 0; i--) {
                double s = t2[i];
                for (int q2 = i + 1; q2 < 12; q2++) s -= dA[q2 * 12 + i] * t2[q2];
                t2[i] = s / dA[i * 12 + i];
            }
            for (int i = 0; i < 12; i++) spara[i * 3 + ch] = (float)t2[i];
        }
    }
    __syncthreads();

    float lsum = 0.0f;
    for (int e = tid; e < 1200; e += 256) {
        int n = e / 48, td = (e % 48) / 3, ch = e % 3;
        float s = 0.0f;
#pragma unroll
        for (int c = 0; c < 12; c++) s = fmaf(sX[n * 192 + td * 12 + c], spara[c * 3 + ch], s);
        ob[((long)(p * 25 + n)) * 48 + td * 3 + ch] = s;
        int yy = py + n / 5 - 2, xx = px + n % 5 - 2;
        float rv = (yy >= 0 && yy < 24 && xx >= 0 && xx < 24)
                       ? gt[(td * 3 + ch) * 576 + yy * 24 + xx] : 0.0f;
        lsum += fabsf(s - rv);
    }
    sred[tid] = lsum;
    __syncthreads();
    for (int s = 128; s >= 1; s >>= 1) {
        if (tid < s) sred[tid] += sred[tid + s];
        __syncthreads();
    }
    if (tid == 0) lp[p] = sred[0];
}

// ---------------- fold (overlap-add) + normalize ----------------
__global__ void fold_kernel(const float* __restrict__ ob, float* __restrict__ out) {
    int idx = blockIdx.x * 256 + threadIdx.x;
    if (idx >= 27648) return;
    int td = idx / 1728;
    int rem = idx % 1728;
    int ch = rem / 576;
    int p = rem % 576;
    int y = p / 24, x = p % 24;
    float num = 0.0f;
    int den = 0;
    for (int i = 0; i < 5; i++) {
        int yy = y + 2 - i;
        if (yy < 0 || yy >= 24) continue;
        for (int j = 0; j < 5; j++) {
            int xx = x + 2 - j;
            if (xx < 0 || xx >= 24) continue;
            num += ob[((long)((yy * 24 + xx) * 25 + i * 5 + j)) * 48 + td * 3 + ch];
            den++;
        }
    }
    out[idx] = num / (float)den;
}

// ---------------- final loss reduce ----------------
__global__ __launch_bounds__(64) void loss_kernel(const float* __restrict__ lp,
                                                  float* __restrict__ out) {
    int t = threadIdx.x;
    float s = 0.0f;
    for (int e = t; e < 576; e += 64) s += lp[e];
#pragma unroll
    for (int d = 32; d >= 1; d >>= 1) s += __shfl_xor(s, d);
    if (t == 0) out[27648] = s / 691200.0f;
}

// ---------------- launch ----------------
extern "C" void kernel_launch(void* const* d_in, const int* in_sizes, int n_in,
                              void* d_out, int out_size, void* d_ws, size_t ws_size,
                              hipStream_t stream) {
    const float* x      = (const float*)d_in[0];
    const float* design = (const float*)d_in[1];
    const float* gt     = (const float*)d_in[2];
    const float* w1     = (const float*)d_in[3];
    const float* b1     = (const float*)d_in[4];
    const float* w2     = (const float*)d_in[5];
    const float* b2     = (const float*)d_in[6];
    const float* w3     = (const float*)d_in[7];
    const float* b3     = (const float*)d_in[8];
    const float* wf     = (const float*)d_in[9];
    const float* bf     = (const float*)d_in[10];
    float* out = (float*)d_out;
    char* wsb  = (char*)d_ws;

    float* part = (float*)(wsb + OFF_PART);
    char*  actX = wsb + OFF_ACTX;
    char*  aF1  = wsb + OFF_AF1;
    char*  aF2  = wsb + OFF_AF2;
    char*  aF3  = wsb + OFF_AF3;
    float* wtT  = (float*)(wsb + OFF_WTT);
    float* dn   = (float*)(wsb + OFF_DN);
    float* ob   = (float*)(wsb + OFF_OB);
    float* mn   = (float*)(wsb + OFF_MN);
    float* mx   = (float*)(wsb + OFF_MX);
    float* lp   = (float*)(wsb + OFF_LP);

    minmax_kernel<<<576, 64, 0, stream>>>(design, mn, mx);
    dnorm_kernel<<<10800, 256, 0, stream>>>(design, mn, mx, dn);

    // x -> bf16 hi/lo padded chunks (160 ch = 5 chunks)
    fact_kernel<<<dim3(5, 11), 256, 0, stream>>>(x, nullptr, actX, 160, 1, 0);
    // conv1: cin=160 (5 chunks): grid (8 ocb,2 px,5 ks), 1 chunk/block
    conv_mfma2_kernel<1><<<dim3(8, 2, 5), 256, 0, stream>>>(actX, w1, part, 160, 1024);
    fact_kernel<<<dim3(32, 11), 256, 0, stream>>>(part, b1, aF1, 1024, 5, 1);
    // conv2: cin=1024 (32 chunks): grid (8,2,16), 2 chunks/block
    conv_mfma2_kernel<2><<<dim3(8, 2, 16), 256, 0, stream>>>(aF1, w2, part, 1024, 1024);
    fact_kernel<<<dim3(32, 11), 256, 0, stream>>>(part, b2, aF2, 1024, 16, 1);
    // conv3
    conv_mfma2_kernel<2><<<dim3(8, 2, 16), 256, 0, stream>>>(aF2, w3, part, 1024, 1024);
    fact_kernel<<<dim3(32, 11), 256, 0, stream>>>(part, b3, aF3, 1024, 16, 1);
    // convf: cout=6400: grid (50,2,4), 8 chunks/block
    conv_mfma2_kernel<8><<<dim3(50, 2, 4), 256, 0, stream>>>(aF3, wf, part, 1024, 6400);
    tanh_tr_kernel<<<dim3(100, 9), dim3(64, 4), 0, stream>>>(part, bf, wtT);

    stagec_kernel<<<576, 256, 0, stream>>>(dn, wtT, x, gt, ob, lp);
    fold_kernel<<<108, 256, 0, stream>>>(ob, out);
    loss_kernel<<<1, 64, 0, stream>>>(lp, out);
}

// Round 4
// 550.820 us; speedup vs baseline: 2.9633x; 2.9633x over previous
//
#include <hip/hip_runtime.h>
#include <math.h>

// ---------------- problem constants ----------------
// b=1, t=16, ch_in=10, h=w=24, t_de=16, ch_de=12, K=5, N=25
// hw=576, M = 14400; out: 27648 + loss = 27649 floats

typedef __attribute__((ext_vector_type(8))) short sh8;
typedef __attribute__((ext_vector_type(4))) float f32x4;

// ---------------- workspace layout (byte offsets) ----------------
#define OFF_PART 0UL              // 58,982,400 (convf: 4 splits x 6400x576x4)
#define OFF_X2T  58982400UL       // 26,542,080 (288 chunks x 92160)
#define OFF_WTT  58982400UL       // overlaps X2T (X2T dead when WTT written)
#define OFF_ACT  85524480UL       // 2,359,296 (1024x576 fp32)
#define OFF_DN   87883776UL       // 11,059,200
#define OFF_OB   98942976UL       // 2,764,800
#define OFF_MN   101707776UL      // 16,128
#define OFF_MX   101723904UL      // 16,128
#define OFF_LP   101740032UL      // 2,304
// total ~101.7 MB

// X2T chunk layout: [kc][hi: 576x80B][lo: 576x80B]  (92160 B per chunk)
// row (kc,px): 32 bf16 halves for k = kc*32..kc*32+31, 16B pad.

// ---------------- helpers ----------------
__device__ inline void glds16(const void* gsrc, void* ldst) {
    __builtin_amdgcn_global_load_lds((const __attribute__((address_space(1))) void*)gsrc,
                                     (__attribute__((address_space(3))) void*)ldst, 16, 0, 0);
}

// ---------------- min/max per pixel for the 7 normalization groups ----------------
__global__ __launch_bounds__(64) void minmax_kernel(const float* __restrict__ design,
                                                    float* __restrict__ mn_o,
                                                    float* __restrict__ mx_o) {
    int p = blockIdx.x;
    int py = p / 24, px = p % 24;
    int lane = threadIdx.x;
    float mn[7], mx[7];
#pragma unroll
    for (int g = 0; g < 7; g++) { mn[g] = 1e30f; mx[g] = -1e30f; }
    for (int e = lane; e < 400; e += 64) {
        int n = e / 16, td = e % 16;
        int yy = py + n / 5 - 2, xx = px + n % 5 - 2;
        bool ok = (yy >= 0 && yy < 24 && xx >= 0 && xx < 24);
#pragma unroll
        for (int cd = 1; cd < 12; cd++) {
            float v = ok ? design[(td * 12 + cd) * 576 + yy * 24 + xx] : 0.0f;
            int g = (cd <= 3) ? 0 : (cd == 4) ? 1 : (cd <= 7) ? 2 : 3 + (cd - 8);
            mn[g] = fminf(mn[g], v);
            mx[g] = fmaxf(mx[g], v);
        }
    }
#pragma unroll
    for (int s = 32; s >= 1; s >>= 1) {
#pragma unroll
        for (int g = 0; g < 7; g++) {
            mn[g] = fminf(mn[g], __shfl_xor(mn[g], s));
            mx[g] = fmaxf(mx[g], __shfl_xor(mx[g], s));
        }
    }
    if (lane == 0) {
#pragma unroll
        for (int g = 0; g < 7; g++) {
            mn_o[p * 7 + g] = mn[g];
            mx_o[p * 7 + g] = mx[g];
        }
    }
}

// ---------------- normalized d: dn[p][n][td][cd] ----------------
__global__ void dnorm_kernel(const float* __restrict__ design,
                             const float* __restrict__ mn,
                             const float* __restrict__ mx,
                             float* __restrict__ dn) {
    int idx = blockIdx.x * 256 + threadIdx.x;
    if (idx >= 14400 * 192) return;
    int cd = idx % 12;
    int td = (idx / 12) % 16;
    int n  = (idx / 192) % 25;
    int p  = idx / 4800;
    int py = p / 24, px = p % 24;
    int yy = py + n / 5 - 2, xx = px + n % 5 - 2;
    float v = (yy >= 0 && yy < 24 && xx >= 0 && xx < 24)
                  ? design[(td * 12 + cd) * 576 + yy * 24 + xx] : 0.0f;
    if (cd >= 1) {
        int g = (cd <= 3) ? 0 : (cd == 4) ? 1 : (cd <= 7) ? 2 : 3 + (cd - 8);
        float a = mn[p * 7 + g], b = mx[p * 7 + g];
        v = (v - a) / (b - a + 0.001f);
    }
    dn[idx] = v;
}

// ---------------- im2col: act fp32 [C][24][24] -> X2T bf16 hi/lo chunk-major ----------------
__global__ __launch_bounds__(256) void im2col_kernel(const float* __restrict__ act,
                                                     char* __restrict__ x2t, int nrows) {
    int row = blockIdx.x * 256 + threadIdx.x;
    if (row >= nrows) return;
    int kc = row / 576, px = row % 576;
    int y = px / 24, x = px % 24;
    int k0 = kc * 32;
    int ic = k0 / 9;
    int tap = k0 - ic * 9;
    sh8 hv[4], lv[4];
#pragma unroll
    for (int e = 0; e < 32; ++e) {
        int dy = tap / 3, dx = tap - dy * 3;
        int yy = y + dy - 1, xx = x + dx - 1;
        float v = (yy >= 0 && yy < 24 && xx >= 0 && xx < 24)
                      ? act[ic * 576 + yy * 24 + xx] : 0.0f;
        unsigned u = __builtin_bit_cast(unsigned, v);
        hv[e / 8][e % 8] = (short)(u >> 16);
        float fh = __builtin_bit_cast(float, u & 0xFFFF0000u);
        lv[e / 8][e % 8] = (short)(__builtin_bit_cast(unsigned, v - fh) >> 16);
        if (++tap == 9) { tap = 0; ++ic; }
    }
    char* dst = x2t + (long)kc * 92160 + (long)px * 80;
#pragma unroll
    for (int s4 = 0; s4 < 4; ++s4) {
        *(sh8*)(dst + s4 * 16) = hv[s4];
        *(sh8*)(dst + 46080 + s4 * 16) = lv[s4];
    }
}

// ---------------- sum K-splits + bias + leaky -> act fp32 ----------------
__global__ void finalize_kernel(const float* __restrict__ part,
                                const float* __restrict__ bias,
                                float* __restrict__ act, int total, int nsplit) {
    int idx = blockIdx.x * 256 + threadIdx.x;
    if (idx >= total) return;
    float s = 0.0f;
    for (int k = 0; k < nsplit; k++) s += part[(long)k * total + idx];
    s += bias[idx / 576];
    act[idx] = s >= 0.0f ? s : 0.01f * s;
}

// ---------------- MFMA GEMM conv (v3): C[cout][576] = W[cout][K] * X2T[K][576] ----------------
// Block: 128 oc x 288 px, 4 waves; wave (wo,wp): 64 oc x 144 px = 4ot x 9j tiles.
// Per K-chunk (32): stage A (weights fp32, 16 KB, XOR-swizzled via pre-swizzled glds src)
// + B (acts bf16 hi/lo, 45 KB, linear 80B rows) -> vmcnt(0) -> barrier -> compute.
// Weights converted fp32->bf16 hi/lo in-register (truncation split, residual ~2^-16).
// 3 MFMAs per k-chunk: Wh*Xh + Wl*Xh + Wh*Xl.
__global__ __launch_bounds__(256, 2)
void conv_mfma3_kernel(const char* __restrict__ x2t,
                       const float* __restrict__ wgt,   // [cout][K] fp32, K = cin*9
                       float* __restrict__ part,        // [ksplit][cout][576]
                       int K, int cps, int cout) {
    __shared__ __align__(1024) char sA[16384];
    __shared__ __align__(1024) char sB[46080];

    const int tid = threadIdx.x;
    const int lane = tid & 63;
    const int w = tid >> 6;
    const int wo = w >> 1, wp = w & 1;
    const int q = lane >> 4, ln15 = lane & 15;
    const int ocb = blockIdx.x, pxh = blockIdx.y, s = blockIdx.z;
    const long K4 = (long)K * 4;
    const int c0 = s * cps;

    const int arow = lane >> 3;          // 0..7 within an 8-row granule
    const int acol = (lane & 7) * 16;    // byte within 128-B row
    const int sw = (ln15 & 7) << 4;      // read-side XOR
    const int bbase = (wp * 144 + ln15) * 80 + q * 16;

    f32x4 acc[4][9];
#pragma unroll
    for (int a = 0; a < 4; ++a)
#pragma unroll
        for (int j = 0; j < 9; ++j) acc[a][j] = f32x4{0.f, 0.f, 0.f, 0.f};

#pragma unroll 1
    for (int cc = c0; cc < c0 + cps; ++cc) {
        __syncthreads();    // all waves done reading sA/sB of previous chunk
        {
            // A: 128 rows x 128 B; source k-byte pre-swizzled so LDS phys is XOR-laid
            const char* wsrc = (const char*)wgt + (long)(ocb * 128) * K4 + (long)cc * 128;
            for (int it = w; it < 16; it += 4) {
                int r = it * 8 + arow;
                glds16(wsrc + (long)r * K4 + (acol ^ ((r & 7) << 4)), sA + it * 1024);
            }
            // B: hi plane [0,23040), lo plane [23040,46080)
            const char* bsrc = x2t + (long)cc * 92160 + pxh * 23040;
            for (int it = w; it < 45; it += 4) {
                int boff = it * 1024 + lane * 16;
                const char* src = (boff < 23040) ? bsrc + boff
                                                 : bsrc + 46080 + (boff - 23040);
                glds16(src, sB + it * 1024);
            }
        }
        asm volatile("s_waitcnt vmcnt(0)" ::: "memory");
        __syncthreads();

        // A fragments: read swizzled fp32, convert to bf16 hi/lo in-register
        sh8 ah[4], al[4];
#pragma unroll
        for (int ot = 0; ot < 4; ++ot) {
            const char* ap = sA + (wo * 64 + ot * 16 + ln15) * 128;
            float4 a0 = *(const float4*)(ap + ((q * 32) ^ sw));
            float4 a1 = *(const float4*)(ap + ((q * 32 + 16) ^ sw));
            float av[8] = {a0.x, a0.y, a0.z, a0.w, a1.x, a1.y, a1.z, a1.w};
#pragma unroll
            for (int e = 0; e < 8; ++e) {
                unsigned u = __builtin_bit_cast(unsigned, av[e]);
                ah[ot][e] = (short)(u >> 16);
                float fh = __builtin_bit_cast(float, u & 0xFFFF0000u);
                al[ot][e] = (short)(__builtin_bit_cast(unsigned, av[e] - fh) >> 16);
            }
        }
        // B fragments + MFMA
#pragma unroll
        for (int j = 0; j < 9; ++j) {
            int ba = bbase + j * (16 * 80);
            sh8 bh = *(const sh8*)(sB + ba);
            sh8 bl = *(const sh8*)(sB + 23040 + ba);
#pragma unroll
            for (int ot = 0; ot < 4; ++ot) {
                acc[ot][j] = __builtin_amdgcn_mfma_f32_16x16x32_bf16(ah[ot], bh, acc[ot][j], 0, 0, 0);
                acc[ot][j] = __builtin_amdgcn_mfma_f32_16x16x32_bf16(al[ot], bh, acc[ot][j], 0, 0, 0);
                acc[ot][j] = __builtin_amdgcn_mfma_f32_16x16x32_bf16(ah[ot], bl, acc[ot][j], 0, 0, 0);
            }
        }
    }
    // epilogue: C row=oc (q*4+vr), col=px (ln15)
#pragma unroll
    for (int ot = 0; ot < 4; ++ot) {
        int oc0 = ocb * 128 + wo * 64 + ot * 16 + q * 4;
#pragma unroll
        for (int j = 0; j < 9; ++j) {
            int px = pxh * 288 + wp * 144 + j * 16 + ln15;
#pragma unroll
            for (int vr = 0; vr < 4; ++vr)
                part[((long)s * cout + oc0 + vr) * 576 + px] = acc[ot][j][vr];
        }
    }
}

// ---------------- tanh + sum 4 splits + transpose: part -> wtT[576][6400] ----------------
__global__ __launch_bounds__(256) void tanh_tr_kernel(const float* __restrict__ part,
                                                      const float* __restrict__ bias,
                                                      float* __restrict__ wtT) {
    __shared__ float tile[64][65];
    int oc0 = blockIdx.x * 64, p0 = blockIdx.y * 64;
    int tx = threadIdx.x, ty = threadIdx.y;
#pragma unroll
    for (int k = 0; k < 16; k++) {
        int row = ty + k * 4;
        float s = 0.f;
#pragma unroll
        for (int sp = 0; sp < 4; ++sp)
            s += part[((long)sp * 6400 + oc0 + row) * 576 + p0 + tx];
        tile[row][tx] = tanhf(s + bias[oc0 + row]);
    }
    __syncthreads();
#pragma unroll
    for (int k = 0; k < 16; k++) {
        int rr = ty + k * 4;
        wtT[(long)(p0 + rr) * 6400 + oc0 + tx] = tile[tx][rr];
    }
}

// ---------------- per-pixel stage: Wm, XTW, A, B, solve, o, loss partial ----------------
__global__ __launch_bounds__(256) void stagec_kernel(const float* __restrict__ dn,
                                                     const float* __restrict__ wtT,
                                                     const float* __restrict__ xin,
                                                     const float* __restrict__ gt,
                                                     float* __restrict__ ob,
                                                     float* __restrict__ lp) {
    int p = blockIdx.x;
    int py = p / 24, px = p % 24;
    int tid = threadIdx.x;
    __shared__ float sX[4800];
    __shared__ float sW[6400];
    __shared__ float sY[1200];
    __shared__ float sP[192];
    __shared__ float sXTW[192];
    __shared__ float sA[144];
    __shared__ float sB[36];
    __shared__ double dA[144];
    __shared__ double db[36];
    __shared__ float spara[36];
    __shared__ float sred[256];

    for (int e = tid; e < 4800; e += 256) sX[e] = dn[(long)p * 4800 + e];
    for (int e = tid; e < 6400; e += 256) sW[e] = wtT[(long)p * 6400 + e];
    for (int e = tid; e < 1200; e += 256) {
        int n = e / 48, t = (e % 48) / 3, ch = e % 3;
        int yy = py + n / 5 - 2, xx = px + n % 5 - 2;
        sY[e] = (yy >= 0 && yy < 24 && xx >= 0 && xx < 24)
                    ? xin[(t * 10 + ch) * 576 + yy * 24 + xx] : 0.0f;
    }
    if (tid < 144) sA[tid] = 0.0f;
    if (tid < 36) sB[tid] = 0.0f;
    __syncthreads();

    for (int n = 0; n < 25; n++) {
        const float* X = sX + n * 192;
        const float* W = sW + n * 256;
        if (tid < 192) {
            int c = tid >> 4, j = tid & 15;
            float s = 0.0f;
#pragma unroll
            for (int t = 0; t < 16; t++) s = fmaf(X[t * 12 + c], W[t * 16 + j], s);
            sP[tid] = s;
        }
        __syncthreads();
        if (tid < 192) {
            int c = tid >> 4, u = tid & 15;
            float s = X[u * 12 + c];
#pragma unroll
            for (int j = 0; j < 16; j++) s = fmaf(sP[c * 16 + j], W[u * 16 + j], s);
            sXTW[tid] = s;
        }
        __syncthreads();
        if (tid < 144) {
            int c = tid / 12, d2 = tid % 12;
            float s = 0.0f;
#pragma unroll
            for (int t = 0; t < 16; t++) s = fmaf(sXTW[c * 16 + t], X[t * 12 + d2], s);
            sA[tid] += s;
        } else if (tid < 180) {
            int e = tid - 144;
            int c = e / 3, ch = e % 3;
            float s = 0.0f;
#pragma unroll
            for (int t = 0; t < 16; t++) s = fmaf(sXTW[c * 16 + t], sY[n * 48 + t * 3 + ch], s);
            sB[e] += s;
        }
        __syncthreads();
    }

    if (tid < 144) dA[tid] = (double)sA[tid] + ((tid % 13 == 0) ? 0.01 : 0.0);
    if (tid < 36) db[tid] = (double)sB[tid];
    __syncthreads();

    if (tid == 0) {
        for (int kk = 0; kk < 12; kk++) {
            double d = dA[kk * 12 + kk];
            for (int q2 = 0; q2 < kk; q2++) d -= dA[kk * 12 + q2] * dA[kk * 12 + q2];
            d = sqrt(d);
            dA[kk * 12 + kk] = d;
            double inv = 1.0 / d;
            for (int i = kk + 1; i < 12; i++) {
                double s = dA[i * 12 + kk];
                for (int q2 = 0; q2 < kk; q2++) s -= dA[i * 12 + q2] * dA[kk * 12 + q2];
                dA[i * 12 + kk] = s * inv;
            }
        }
        for (int ch = 0; ch < 3; ch++) {
            double t2[12];
            for (int i = 0; i < 12; i++) {
                double s = db[i * 3 + ch];
                for (int q2 = 0; q2 < i; q2++) s -= dA[i * 12 + q2] * t2[q2];
                t2[i] = s / dA[i * 12 + i];
            }
            for (int i = 11; i >= 0; i--) {
                double s = t2[i];
                for (int q2 = i + 1; q2 < 12; q2++) s -= dA[q2 * 12 + i] * t2[q2];
                t2[i] = s / dA[i * 12 + i];
            }
            for (int i = 0; i < 12; i++) spara[i * 3 + ch] = (float)t2[i];
        }
    }
    __syncthreads();

    float lsum = 0.0f;
    for (int e = tid; e < 1200; e += 256) {
        int n = e / 48, td = (e % 48) / 3, ch = e % 3;
        float s = 0.0f;
#pragma unroll
        for (int c = 0; c < 12; c++) s = fmaf(sX[n * 192 + td * 12 + c], spara[c * 3 + ch], s);
        ob[((long)(p * 25 + n)) * 48 + td * 3 + ch] = s;
        int yy = py + n / 5 - 2, xx = px + n % 5 - 2;
        float rv = (yy >= 0 && yy < 24 && xx >= 0 && xx < 24)
                       ? gt[(td * 3 + ch) * 576 + yy * 24 + xx] : 0.0f;
        lsum += fabsf(s - rv);
    }
    sred[tid] = lsum;
    __syncthreads();
    for (int s = 128; s >= 1; s >>= 1) {
        if (tid < s) sred[tid] += sred[tid + s];
        __syncthreads();
    }
    if (tid == 0) lp[p] = sred[0];
}

// ---------------- fold (overlap-add) + normalize ----------------
__global__ void fold_kernel(const float* __restrict__ ob, float* __restrict__ out) {
    int idx = blockIdx.x * 256 + threadIdx.x;
    if (idx >= 27648) return;
    int td = idx / 1728;
    int rem = idx % 1728;
    int ch = rem / 576;
    int p = rem % 576;
    int y = p / 24, x = p % 24;
    float num = 0.0f;
    int den = 0;
    for (int i = 0; i < 5; i++) {
        int yy = y + 2 - i;
        if (yy < 0 || yy >= 24) continue;
        for (int j = 0; j < 5; j++) {
            int xx = x + 2 - j;
            if (xx < 0 || xx >= 24) continue;
            num += ob[((long)((yy * 24 + xx) * 25 + i * 5 + j)) * 48 + td * 3 + ch];
            den++;
        }
    }
    out[idx] = num / (float)den;
}

// ---------------- final loss reduce ----------------
__global__ __launch_bounds__(64) void loss_kernel(const float* __restrict__ lp,
                                                  float* __restrict__ out) {
    int t = threadIdx.x;
    float s = 0.0f;
    for (int e = t; e < 576; e += 64) s += lp[e];
#pragma unroll
    for (int d = 32; d >= 1; d >>= 1) s += __shfl_xor(s, d);
    if (t == 0) out[27648] = s / 691200.0f;
}

// ---------------- launch ----------------
extern "C" void kernel_launch(void* const* d_in, const int* in_sizes, int n_in,
                              void* d_out, int out_size, void* d_ws, size_t ws_size,
                              hipStream_t stream) {
    const float* x      = (const float*)d_in[0];
    const float* design = (const float*)d_in[1];
    const float* gt     = (const float*)d_in[2];
    const float* w1     = (const float*)d_in[3];
    const float* b1     = (const float*)d_in[4];
    const float* w2     = (const float*)d_in[5];
    const float* b2     = (const float*)d_in[6];
    const float* w3     = (const float*)d_in[7];
    const float* b3     = (const float*)d_in[8];
    const float* wf     = (const float*)d_in[9];
    const float* bf     = (const float*)d_in[10];
    float* out = (float*)d_out;
    char* wsb  = (char*)d_ws;

    float* part = (float*)(wsb + OFF_PART);
    char*  x2t  = wsb + OFF_X2T;
    float* wtT  = (float*)(wsb + OFF_WTT);
    float* act  = (float*)(wsb + OFF_ACT);
    float* dn   = (float*)(wsb + OFF_DN);
    float* ob   = (float*)(wsb + OFF_OB);
    float* mn   = (float*)(wsb + OFF_MN);
    float* mx   = (float*)(wsb + OFF_MX);
    float* lp   = (float*)(wsb + OFF_LP);

    minmax_kernel<<<576, 64, 0, stream>>>(design, mn, mx);
    dnorm_kernel<<<10800, 256, 0, stream>>>(design, mn, mx, dn);

    // conv1: K=1440 (45 chunks), ksplit=15 x cps=3
    im2col_kernel<<<102, 256, 0, stream>>>(x, x2t, 45 * 576);
    conv_mfma3_kernel<<<dim3(8, 2, 15), 256, 0, stream>>>(x2t, w1, part, 1440, 3, 1024);
    finalize_kernel<<<2304, 256, 0, stream>>>(part, b1, act, 589824, 15);
    // conv2: K=9216 (288 chunks), ksplit=16 x cps=18
    im2col_kernel<<<648, 256, 0, stream>>>(act, x2t, 288 * 576);
    conv_mfma3_kernel<<<dim3(8, 2, 16), 256, 0, stream>>>(x2t, w2, part, 9216, 18, 1024);
    finalize_kernel<<<2304, 256, 0, stream>>>(part, b2, act, 589824, 16);
    // conv3
    im2col_kernel<<<648, 256, 0, stream>>>(act, x2t, 288 * 576);
    conv_mfma3_kernel<<<dim3(8, 2, 16), 256, 0, stream>>>(x2t, w3, part, 9216, 18, 1024);
    finalize_kernel<<<2304, 256, 0, stream>>>(part, b3, act, 589824, 16);
    // convf: cout=6400, ksplit=4 x cps=72
    im2col_kernel<<<648, 256, 0, stream>>>(act, x2t, 288 * 576);
    conv_mfma3_kernel<<<dim3(50, 2, 4), 256, 0, stream>>>(x2t, wf, part, 9216, 72, 6400);
    tanh_tr_kernel<<<dim3(100, 9), dim3(64, 4), 0, stream>>>(part, bf, wtT);

    stagec_kernel<<<576, 256, 0, stream>>>(dn, wtT, x, gt, ob, lp);
    fold_kernel<<<108, 256, 0, stream>>>(ob, out);
    loss_kernel<<<1, 64, 0, stream>>>(lp, out);
}